// Round 8
// baseline (346.619 us; speedup 1.0000x reference)
//
#include <hip/hip_runtime.h>
#include <hip/hip_fp16.h>
#include <math.h>

// GAT 2-layer, N=50000, E=800000 (+N self loops), IN=128, HID=32, HEADS=4, OUT=32
#define NN   50000
#define EE   800000
#define ETOT 850000          // EE + NN
#define NEG  0.2f
#define SCAN_BLOCKS ((NN + 255) / 256)   // 196

// -------- workspace layout (element offsets, 4B units; ints/halfs alias floats) --------
// zero-initialized region (one contiguous memset):
#define O_DEG    0           //    50,000  in-degree per node (int, EXCLUDING self-loop)
#define O_EASUM  50000       //         4  edge_attr sum (scalar)
#define ZERO_ELEMS 50004
// non-zeroed:
#define O_COEF   50004       //         8  coef1[4], coef2 at [4]
#define O_ROWPTR 50012       //    50,001  CSR row pointers (int)
#define O_CURSOR 100016      //    50,000  fill cursors (int)
#define O_BLKSUM 150016      //       256  per-block scan totals (int)
#define O_BLKOFF 150272      //       256  per-block scan offsets (int)
#define O_CSRSE  150528      // 1,700,000  packed (src:int, ea:float) per CSR slot (uint2)
#define O_ASRC1  1850528     //   200,000  per-node src logits layer1 [N][4]
#define O_ADST1  2050528     //   200,000  per-node dst logits layer1 [N][4]
#define O_XLH    2250528     // 3,200,000  layer-1 features fp16 [N][128] (6.4M halfs)
#define O_OUT1   5450528     // 6,400,000  layer-1 agg output fp32 [N][128]
#define O_HLH    11850528    //   800,000  layer-2 features fp16 [N][32] (1.6M halfs)
#define O_ASRC2  12650528    //    50,000  per-node src logits layer2
#define O_ADST2  12700528    //    50,000  per-node dst logits layer2
#define WS_ELEMS 12750528    // ~51 MB

// -------------------- fused: edge_attr sum + degree count, 1 thread/edge ---------------
__global__ __launch_bounds__(256) void k_ea_count(
    const float* __restrict__ ea, const int* __restrict__ ei,
    float* __restrict__ easum, int* __restrict__ deg) {
  __shared__ float red[4];
  int e = blockIdx.x * 256 + threadIdx.x;
  float s = 0.f;
  if (e < EE) {
    s = ea[e];
    atomicAdd(deg + ei[EE + e], 1);
  }
  #pragma unroll
  for (int o = 32; o > 0; o >>= 1) s += __shfl_down(s, o, 64);
  if ((threadIdx.x & 63) == 0) red[threadIdx.x >> 6] = s;
  __syncthreads();
  if (threadIdx.x == 0) atomicAdd(easum, red[0] + red[1] + red[2] + red[3]);
}

// -------------------- edge-coef precompute --------------------
__global__ void k_coef(const float* __restrict__ lew1, const float* __restrict__ ae1,
                       const float* __restrict__ lew2, const float* __restrict__ ae2,
                       float* __restrict__ coef) {
  int t = threadIdx.x; // 128 threads
  float p = lew1[t] * ae1[t];
  #pragma unroll
  for (int o = 16; o > 0; o >>= 1) p += __shfl_down(p, o, 32);
  if ((t & 31) == 0) coef[t >> 5] = p;
  if (t < 32) {
    float q = lew2[t] * ae2[t];
    #pragma unroll
    for (int o = 16; o > 0; o >>= 1) q += __shfl_down(q, o, 32);
    if (t == 0) coef[4] = q;
  }
}

// -------------------- multi-block exclusive scan of (deg+1) --------------------
__device__ __forceinline__ int wave_incl_scan(int v, int lane) {
  #pragma unroll
  for (int o = 1; o < 64; o <<= 1) {
    int u = __shfl_up(v, o, 64);
    if (lane >= o) v += u;
  }
  return v;
}

__global__ __launch_bounds__(256) void k_scan_blk(const int* __restrict__ deg,
                                                  int* __restrict__ rowptr,
                                                  int* __restrict__ blksum) {
  __shared__ int wsum[4];
  const int t = threadIdx.x;
  const int i = blockIdx.x * 256 + t;
  const int lane = t & 63, wv = t >> 6;
  int v = (i < NN) ? (deg[i] + 1) : 0;       // +1 = self-loop
  int incl = wave_incl_scan(v, lane);
  if (lane == 63) wsum[wv] = incl;
  __syncthreads();
  int off = 0;
  #pragma unroll
  for (int k = 0; k < 4; ++k) if (k < wv) off += wsum[k];
  incl += off;
  if (i < NN) rowptr[i] = incl - v;          // local exclusive
  if (t == 255) blksum[blockIdx.x] = incl;   // block total
}

__global__ __launch_bounds__(256) void k_scan_top(const int* __restrict__ blksum,
                                                  int* __restrict__ blkoff) {
  __shared__ int wsum[4];
  const int t = threadIdx.x;
  const int lane = t & 63, wv = t >> 6;
  int v = (t < SCAN_BLOCKS) ? blksum[t] : 0;
  int incl = wave_incl_scan(v, lane);
  if (lane == 63) wsum[wv] = incl;
  __syncthreads();
  int off = 0;
  #pragma unroll
  for (int k = 0; k < 4; ++k) if (k < wv) off += wsum[k];
  incl += off;
  if (t < SCAN_BLOCKS) blkoff[t] = incl - v;
}

__global__ __launch_bounds__(256) void k_scan_add(int* __restrict__ rowptr,
                                                  int* __restrict__ cursor,
                                                  const int* __restrict__ blkoff) {
  const int i = blockIdx.x * 256 + threadIdx.x;
  if (i < NN) {
    int r = rowptr[i] + blkoff[blockIdx.x];
    rowptr[i] = r;
    cursor[i] = r;
  }
  if (i == 0) rowptr[NN] = ETOT;
}

// fill CSR: ONE packed 8B store per edge (src + edge attr), self-loop attr = mean
__global__ void k_fill(const int* __restrict__ ei, const float* __restrict__ eattr,
                       const float* __restrict__ easum, int* __restrict__ cursor,
                       uint2* __restrict__ csr_se) {
  int e = blockIdx.x * 256 + threadIdx.x;
  if (e >= ETOT) return;
  int s, d; float ea;
  if (e < EE) { s = ei[e]; d = ei[EE + e]; ea = eattr[e]; }
  else { s = d = e - EE; ea = easum[0] * (1.f / EE); }
  int slot = atomicAdd(cursor + d, 1);
  csr_se[slot] = make_uint2((unsigned)s, __float_as_uint(ea));
}

// 32 FMAs against one uniform W row of 32 floats
#define GEMM_STEP(WB, K, XS) {                                              \
    const float4* Wr = (const float4*)((WB) + (size_t)(K));                 \
    _Pragma("unroll")                                                       \
    for (int j4 = 0; j4 < 8; ++j4) {                                        \
      float4 wv = Wr[j4];                                                   \
      acc[j4 * 4 + 0] += (XS) * wv.x;                                       \
      acc[j4 * 4 + 1] += (XS) * wv.y;                                       \
      acc[j4 * 4 + 2] += (XS) * wv.z;                                       \
      acc[j4 * 4 + 3] += (XS) * wv.w;                                       \
    } }

// -------------------- layer-1 GEMM: xl(fp16) = x @ W1, plus per-node logits -------------
// 1 wave per block; head varies SLOWEST across grid (x re-reads hit L3);
// lane = node; wave-uniform W -> scalar loads; NO LDS, no barriers.
#define L1_NB ((NN + 63) / 64)      // 782 node-blocks per head
__global__ __launch_bounds__(64) void k_lin1(
    const float* __restrict__ x, const float* __restrict__ W,
    const float* __restrict__ att_src, const float* __restrict__ att_dst,
    __half* __restrict__ xlh, float* __restrict__ asrc, float* __restrict__ adst) {
  const int bid = blockIdx.x;
  const int h   = bid / L1_NB;                // head (uniform, slowest)
  const int n   = (bid % L1_NB) * 64 + threadIdx.x;
  const int nc  = n < NN ? n : NN - 1;
  const float4* xr = (const float4*)(x + (size_t)nc * 128);
  const float*  Wh = W + h * 32;              // uniform base
  float acc[32];
  #pragma unroll
  for (int j = 0; j < 32; ++j) acc[j] = 0.f;
  float4 xv = xr[0];
  for (int kt = 0; kt < 32; ++kt) {
    float4 cur = xv;
    if (kt < 31) xv = xr[kt + 1];             // prefetch next 16B of x
    GEMM_STEP(Wh, (kt * 4 + 0) * 128, cur.x);
    GEMM_STEP(Wh, (kt * 4 + 1) * 128, cur.y);
    GEMM_STEP(Wh, (kt * 4 + 2) * 128, cur.z);
    GEMM_STEP(Wh, (kt * 4 + 3) * 128, cur.w);
  }
  if (n < NN) {
    __align__(16) __half hbuf[32];
    #pragma unroll
    for (int j = 0; j < 32; ++j) hbuf[j] = __float2half_rn(acc[j]);
    float4* dst = (float4*)(xlh + (size_t)n * 128 + h * 32);   // 64 B, 16B-aligned
    #pragma unroll
    for (int i = 0; i < 4; ++i) dst[i] = ((const float4*)hbuf)[i];
    float ss = 0.f, sd = 0.f;
    #pragma unroll
    for (int j = 0; j < 32; ++j) {
      ss += acc[j] * att_src[h * 32 + j];     // uniform
      sd += acc[j] * att_dst[h * 32 + j];
    }
    asrc[n * 4 + h] = ss;
    adst[n * 4 + h] = sd;
  }
}

// -------------------- layer-1 aggregation (fused softmax), batch-4 pipelined ------------
// half-wave per node, lane = 4 channels; per batch: 4 packed (src,ea) loads ->
// 4 indep asrc loads + 4 indep row gathers -> math. Tail masked branch-free.
__global__ __launch_bounds__(256) void k_agg1(
    const int* __restrict__ rowptr, const uint2* __restrict__ csr_se,
    const float* __restrict__ asrc, const float* __restrict__ adst,
    const float* __restrict__ coef,
    const __half* __restrict__ xlh, float* __restrict__ out1) {
  int n = blockIdx.x * 8 + (threadIdx.x >> 5);
  if (n >= NN) return;
  int l = threadIdx.x & 31;
  int c4 = l << 2;                    // 4 channels per lane, 32 lanes = 128 ch
  int h = l >> 3;                     // head of this channel group
  float cf = coef[h];
  float ad = adst[(size_t)n * 4 + h];
  int r0 = rowptr[n], r1 = rowptr[n + 1];   // r1 > r0 (self-loop)
  float a0 = 0.f, a1 = 0.f, a2 = 0.f, a3 = 0.f, den = 0.f;
  for (int j = r0; j < r1; j += 4) {
    int sv[4]; float eav[4], asv[4]; uint2 raw[4];
    #pragma unroll
    for (int k = 0; k < 4; ++k) {
      int jj = (j + k < r1) ? (j + k) : (r1 - 1);
      uint2 se = csr_se[jj];
      sv[k] = (int)se.x;
      eav[k] = __uint_as_float(se.y);
    }
    #pragma unroll
    for (int k = 0; k < 4; ++k) {
      asv[k] = asrc[(size_t)sv[k] * 4 + h];
      raw[k] = *(const uint2*)(xlh + (size_t)sv[k] * 128 + c4);   // 4 halfs
    }
    #pragma unroll
    for (int k = 0; k < 4; ++k) {
      float alpha = asv[k] + ad + eav[k] * cf;
      alpha = alpha > 0.f ? alpha : NEG * alpha;
      float ex = (j + k < r1) ? __expf(alpha) : 0.f;   // tail mask
      __half2 p0, p1;
      *(unsigned int*)&p0 = raw[k].x;
      *(unsigned int*)&p1 = raw[k].y;
      float2 f0 = __half22float2(p0), f1 = __half22float2(p1);
      a0 += ex * f0.x;
      a1 += ex * f0.y;
      a2 += ex * f1.x;
      a3 += ex * f1.y;
      den += ex;
    }
  }
  float inv = 1.f / den;
  *(float4*)(out1 + (size_t)n * 128 + c4) = make_float4(a0 * inv, a1 * inv, a2 * inv, a3 * inv);
}

// -------------------- layer-2 GEMM: hl(fp16) = elu(out1+bias1) @ W2, plus logits --------
__global__ __launch_bounds__(64) void k_lin2(
    const float* __restrict__ out1, const float* __restrict__ bias1,
    const float* __restrict__ W2,
    const float* __restrict__ as2w, const float* __restrict__ ad2w,
    __half* __restrict__ hlh, float* __restrict__ asrc2, float* __restrict__ adst2) {
  const int n  = blockIdx.x * 64 + threadIdx.x;
  const int nc = n < NN ? n : NN - 1;
  const float4* xr = (const float4*)(out1 + (size_t)nc * 128);
  const float4* br = (const float4*)bias1;   // uniform
  float acc[32];
  #pragma unroll
  for (int j = 0; j < 32; ++j) acc[j] = 0.f;
  float4 xv = xr[0];
  for (int kt = 0; kt < 32; ++kt) {
    float4 cur = xv;
    if (kt < 31) xv = xr[kt + 1];
    float4 b = br[kt];                       // uniform
    cur.x += b.x; cur.y += b.y; cur.z += b.z; cur.w += b.w;
    cur.x = cur.x > 0.f ? cur.x : (expf(cur.x) - 1.f);   // ELU (once per element)
    cur.y = cur.y > 0.f ? cur.y : (expf(cur.y) - 1.f);
    cur.z = cur.z > 0.f ? cur.z : (expf(cur.z) - 1.f);
    cur.w = cur.w > 0.f ? cur.w : (expf(cur.w) - 1.f);
    GEMM_STEP(W2, (kt * 4 + 0) * 32, cur.x);
    GEMM_STEP(W2, (kt * 4 + 1) * 32, cur.y);
    GEMM_STEP(W2, (kt * 4 + 2) * 32, cur.z);
    GEMM_STEP(W2, (kt * 4 + 3) * 32, cur.w);
  }
  if (n < NN) {
    __align__(16) __half hbuf[32];
    #pragma unroll
    for (int j = 0; j < 32; ++j) hbuf[j] = __float2half_rn(acc[j]);
    float4* dst = (float4*)(hlh + (size_t)n * 32);   // 64 B
    #pragma unroll
    for (int i = 0; i < 4; ++i) dst[i] = ((const float4*)hbuf)[i];
    float ps = 0.f, pd = 0.f;
    #pragma unroll
    for (int j = 0; j < 32; ++j) {
      ps += acc[j] * as2w[j];                // uniform
      pd += acc[j] * ad2w[j];
    }
    asrc2[n] = ps;
    adst2[n] = pd;
  }
}

// -------------------- layer-2 aggregation (fused softmax), batch-4 pipelined ------------
__global__ __launch_bounds__(256) void k_agg2(
    const int* __restrict__ rowptr, const uint2* __restrict__ csr_se,
    const float* __restrict__ asrc2, const float* __restrict__ adst2,
    const float* __restrict__ coef,
    const __half* __restrict__ hlh, const float* __restrict__ bias2,
    float* __restrict__ out) {
  int n = blockIdx.x * 32 + (threadIdx.x >> 3);
  if (n >= NN) return;
  int c4 = (threadIdx.x & 7) << 2;
  float cf = coef[4];
  float ad = adst2[n];
  int r0 = rowptr[n], r1 = rowptr[n + 1];
  float a0 = 0.f, a1 = 0.f, a2 = 0.f, a3 = 0.f, den = 0.f;
  for (int j = r0; j < r1; j += 4) {
    int sv[4]; float eav[4], asv[4]; uint2 raw[4];
    #pragma unroll
    for (int k = 0; k < 4; ++k) {
      int jj = (j + k < r1) ? (j + k) : (r1 - 1);
      uint2 se = csr_se[jj];
      sv[k] = (int)se.x;
      eav[k] = __uint_as_float(se.y);
    }
    #pragma unroll
    for (int k = 0; k < 4; ++k) {
      asv[k] = asrc2[sv[k]];
      raw[k] = *(const uint2*)(hlh + (size_t)sv[k] * 32 + c4);   // 4 halfs
    }
    #pragma unroll
    for (int k = 0; k < 4; ++k) {
      float alpha = asv[k] + ad + eav[k] * cf;
      alpha = alpha > 0.f ? alpha : NEG * alpha;
      float ex = (j + k < r1) ? __expf(alpha) : 0.f;   // tail mask
      __half2 p0, p1;
      *(unsigned int*)&p0 = raw[k].x;
      *(unsigned int*)&p1 = raw[k].y;
      float2 f0 = __half22float2(p0), f1 = __half22float2(p1);
      a0 += ex * f0.x;
      a1 += ex * f0.y;
      a2 += ex * f1.x;
      a3 += ex * f1.y;
      den += ex;
    }
  }
  float inv = 1.f / den;
  float4 b = *(const float4*)(bias2 + c4);
  *(float4*)(out + (size_t)n * 32 + c4) =
      make_float4(a0 * inv + b.x, a1 * inv + b.y, a2 * inv + b.z, a3 * inv + b.w);
}

extern "C" void kernel_launch(void* const* d_in, const int* in_sizes, int n_in,
                              void* d_out, int out_size, void* d_ws, size_t ws_size,
                              hipStream_t stream) {
  const float* x        = (const float*)d_in[0];
  const int*   ei       = (const int*)d_in[1];
  const float* eattr    = (const float*)d_in[2];
  const float* lin1_w   = (const float*)d_in[3];
  const float* att1_src = (const float*)d_in[4];
  const float* att1_dst = (const float*)d_in[5];
  const float* lin1_ew  = (const float*)d_in[6];
  const float* att1_e   = (const float*)d_in[7];
  const float* bias1    = (const float*)d_in[8];
  const float* lin2_w   = (const float*)d_in[9];
  const float* att2_src = (const float*)d_in[10];
  const float* att2_dst = (const float*)d_in[11];
  const float* lin2_ew  = (const float*)d_in[12];
  const float* att2_e   = (const float*)d_in[13];
  const float* bias2    = (const float*)d_in[14];
  float* out = (float*)d_out;
  float* ws  = (float*)d_ws;
  int*   wsi = (int*)d_ws;

  int*    deg     = wsi + O_DEG;
  float*  easum   = ws + O_EASUM;
  float*  coef    = ws + O_COEF;
  int*    rowptr  = wsi + O_ROWPTR;
  int*    cursor  = wsi + O_CURSOR;
  int*    blksum  = wsi + O_BLKSUM;
  int*    blkoff  = wsi + O_BLKOFF;
  uint2*  csr_se  = (uint2*)(wsi + O_CSRSE);
  float*  asrc1   = ws + O_ASRC1;
  float*  adst1   = ws + O_ADST1;
  __half* xlh     = (__half*)(ws + O_XLH);
  float*  out1    = ws + O_OUT1;
  __half* hlh     = (__half*)(ws + O_HLH);
  float*  asrc2   = ws + O_ASRC2;
  float*  adst2   = ws + O_ADST2;

  // zero deg/easum (ws poisoned 0xAA each call)
  hipMemsetAsync(ws, 0, (size_t)ZERO_ELEMS * sizeof(float), stream);

  k_ea_count<<<(EE + 255) / 256, 256, 0, stream>>>(eattr, ei, easum, deg);
  k_coef<<<1, 128, 0, stream>>>(lin1_ew, att1_e, lin2_ew, att2_e, coef);

  // CSR build (dst-sorted): multi-block scan
  k_scan_blk<<<SCAN_BLOCKS, 256, 0, stream>>>(deg, rowptr, blksum);
  k_scan_top<<<1, 256, 0, stream>>>(blksum, blkoff);
  k_scan_add<<<SCAN_BLOCKS, 256, 0, stream>>>(rowptr, cursor, blkoff);
  k_fill<<<(ETOT + 255) / 256, 256, 0, stream>>>(ei, eattr, easum, cursor, csr_se);

  // layer 1
  k_lin1<<<L1_NB * 4, 64, 0, stream>>>(x, lin1_w, att1_src, att1_dst, xlh, asrc1, adst1);
  k_agg1<<<(NN + 7) / 8, 256, 0, stream>>>(rowptr, csr_se, asrc1, adst1, coef, xlh, out1);

  // layer 2
  k_lin2<<<(NN + 63) / 64, 64, 0, stream>>>(out1, bias1, lin2_w, att2_src, att2_dst, hlh, asrc2, adst2);
  k_agg2<<<(NN + 31) / 32, 256, 0, stream>>>(rowptr, csr_se, asrc2, adst2, coef, hlh, bias2, out);
}

// Round 9
// 316.851 us; speedup vs baseline: 1.0940x; 1.0940x over previous
//
#include <hip/hip_runtime.h>
#include <hip/hip_fp16.h>
#include <math.h>

// GAT 2-layer, N=50000, E=800000 (+N self loops), IN=128, HID=32, HEADS=4, OUT=32
#define NN   50000
#define EE   800000
#define ETOT 850000          // EE + NN
#define NEG  0.2f
#define SCAN_BLOCKS ((NN + 255) / 256)   // 196

// -------- workspace layout (element offsets, 4B units; ints/halfs alias floats) --------
// zero-initialized region (one contiguous memset):
#define O_DEG    0           //    50,000  in-degree per node (int, EXCLUDING self-loop)
#define O_EASUM  50000       //         4  edge_attr sum (scalar)
#define ZERO_ELEMS 50004
// non-zeroed:
#define O_COEF   50004       //         8  coef1[4], coef2 at [4]
#define O_ROWPTR 50012       //    50,001  CSR row pointers (int)
#define O_CURSOR 100016      //    50,000  fill cursors (int)
#define O_BLKSUM 150016      //       256  per-block scan totals (int)
#define O_BLKOFF 150272      //       256  per-block scan offsets (int)
#define O_CSRSRC 150528      //   850,000  src node per CSR slot (int)
#define O_EASLOT 1000528     //   850,000  edge attr in CSR slot order (float)
#define O_ASRC1  1850528     //   200,000  per-node src logits layer1 [N][4]
#define O_ADST1  2050528     //   200,000  per-node dst logits layer1 [N][4]
#define O_XLH    2250528     // 3,200,000  layer-1 features fp16 [N][128] (6.4M halfs)
#define O_OUT1   5450528     // 6,400,000  layer-1 agg output fp32 [N][128]
#define O_HLH    11850528    //   800,000  layer-2 features fp16 [N][32] (1.6M halfs)
#define O_ASRC2  12650528    //    50,000  per-node src logits layer2
#define O_ADST2  12700528    //    50,000  per-node dst logits layer2
#define WS_ELEMS 12750528    // ~51 MB

// -------------------- fused: edge_attr sum + degree count (grid-stride, R7-proven) -----
__global__ void k_ea_count(const float* __restrict__ ea, const int* __restrict__ ei,
                           float* __restrict__ easum, int* __restrict__ deg) {
  __shared__ float red[4];
  float s = 0.f;
  int stride = gridDim.x * blockDim.x;
  for (int i = blockIdx.x * blockDim.x + threadIdx.x; i < EE; i += stride) {
    s += ea[i];
    atomicAdd(deg + ei[EE + i], 1);
  }
  #pragma unroll
  for (int o = 32; o > 0; o >>= 1) s += __shfl_down(s, o, 64);
  if ((threadIdx.x & 63) == 0) red[threadIdx.x >> 6] = s;
  __syncthreads();
  if (threadIdx.x == 0) atomicAdd(easum, red[0] + red[1] + red[2] + red[3]);
}

// -------------------- multi-block exclusive scan of (deg+1) --------------------
__device__ __forceinline__ int wave_incl_scan(int v, int lane) {
  #pragma unroll
  for (int o = 1; o < 64; o <<= 1) {
    int u = __shfl_up(v, o, 64);
    if (lane >= o) v += u;
  }
  return v;
}

__global__ __launch_bounds__(256) void k_scan_blk(const int* __restrict__ deg,
                                                  int* __restrict__ rowptr,
                                                  int* __restrict__ blksum) {
  __shared__ int wsum[4];
  const int t = threadIdx.x;
  const int i = blockIdx.x * 256 + t;
  const int lane = t & 63, wv = t >> 6;
  int v = (i < NN) ? (deg[i] + 1) : 0;       // +1 = self-loop
  int incl = wave_incl_scan(v, lane);
  if (lane == 63) wsum[wv] = incl;
  __syncthreads();
  int off = 0;
  #pragma unroll
  for (int k = 0; k < 4; ++k) if (k < wv) off += wsum[k];
  incl += off;
  if (i < NN) rowptr[i] = incl - v;          // local exclusive
  if (t == 255) blksum[blockIdx.x] = incl;   // block total
}

// scan of block totals + (piggybacked) edge-coef precompute
__global__ __launch_bounds__(256) void k_scan_top(
    const int* __restrict__ blksum, int* __restrict__ blkoff,
    const float* __restrict__ lew1, const float* __restrict__ ae1,
    const float* __restrict__ lew2, const float* __restrict__ ae2,
    float* __restrict__ coef) {
  __shared__ int wsum[4];
  const int t = threadIdx.x;
  const int lane = t & 63, wv = t >> 6;
  int v = (t < SCAN_BLOCKS) ? blksum[t] : 0;
  int incl = wave_incl_scan(v, lane);
  if (lane == 63) wsum[wv] = incl;
  __syncthreads();
  int off = 0;
  #pragma unroll
  for (int k = 0; k < 4; ++k) if (k < wv) off += wsum[k];
  incl += off;
  if (t < SCAN_BLOCKS) blkoff[t] = incl - v;
  // coef (threads 0..127): coef1[h] = sum_c lew1[h*32+c]*ae1[h*32+c]; coef2 at [4]
  if (t < 128) {
    float p = lew1[t] * ae1[t];
    #pragma unroll
    for (int o = 16; o > 0; o >>= 1) p += __shfl_down(p, o, 32);
    if ((t & 31) == 0) coef[t >> 5] = p;
    if (t < 32) {
      float q = lew2[t] * ae2[t];
      #pragma unroll
      for (int o = 16; o > 0; o >>= 1) q += __shfl_down(q, o, 32);
      if (t == 0) coef[4] = q;
    }
  }
}

// add block offsets; init cursor; write DETERMINISTIC self-loop at last slot of each row
__global__ __launch_bounds__(256) void k_scan_add(
    int* __restrict__ rowptr, int* __restrict__ cursor,
    const int* __restrict__ blkoff, const int* __restrict__ deg,
    const float* __restrict__ easum,
    int* __restrict__ csr_src, float* __restrict__ ea_slot) {
  const int i = blockIdx.x * 256 + threadIdx.x;
  if (i < NN) {
    int r = rowptr[i] + blkoff[blockIdx.x];
    rowptr[i] = r;
    cursor[i] = r;
    int slot = r + deg[i];            // last slot of row i = self-loop
    csr_src[slot] = i;
    ea_slot[slot] = easum[0] * (1.f / EE);
  }
  if (i == 0) rowptr[NN] = ETOT;
}

// 32 FMAs against one uniform W row of 32 floats
#define GEMM_STEP(WB, K, XS) {                                              \
    const float4* Wr = (const float4*)((WB) + (size_t)(K));                 \
    _Pragma("unroll")                                                       \
    for (int j4 = 0; j4 < 8; ++j4) {                                        \
      float4 wv = Wr[j4];                                                   \
      acc[j4 * 4 + 0] += (XS) * wv.x;                                       \
      acc[j4 * 4 + 1] += (XS) * wv.y;                                       \
      acc[j4 * 4 + 2] += (XS) * wv.z;                                       \
      acc[j4 * 4 + 3] += (XS) * wv.w;                                       \
    } }

// -------------------- FUSED: layer-1 GEMM  ∥  CSR fill (independent work) ---------------
// blocks [0, LIN1B): lin1 — 1 wave, head = bid/L1_NB (uniform), lane = node, no LDS.
// blocks [LIN1B, LIN1B+FILLB): fill — 64 edges/block, cursor atomic + 2 stores.
// The fill scatter's L2-atomic latency hides under lin1's VALU work (co-resident waves).
#define L1_NB ((NN + 63) / 64)      // 782 node-blocks per head
#define LIN1B (L1_NB * 4)           // 3128
#define FILLB ((EE + 63) / 64)      // 12500
__global__ __launch_bounds__(64) void k_fused(
    const float* __restrict__ x, const float* __restrict__ W,
    const float* __restrict__ att_src, const float* __restrict__ att_dst,
    __half* __restrict__ xlh, float* __restrict__ asrc, float* __restrict__ adst,
    const int* __restrict__ ei, const float* __restrict__ eattr,
    int* __restrict__ cursor, int* __restrict__ csr_src, float* __restrict__ ea_slot) {
  const int bid = blockIdx.x;
  if (bid >= LIN1B) {                         // ---- fill path ----
    int e = (bid - LIN1B) * 64 + threadIdx.x;
    if (e < EE) {
      int s = ei[e];
      int d = ei[EE + e];
      float ea = eattr[e];
      int slot = atomicAdd(cursor + d, 1);
      csr_src[slot] = s;
      ea_slot[slot] = ea;
    }
    return;
  }
  // ---- lin1 path ----
  const int h   = bid / L1_NB;                // head (uniform, slowest)
  const int n   = (bid % L1_NB) * 64 + threadIdx.x;
  const int nc  = n < NN ? n : NN - 1;
  const float4* xr = (const float4*)(x + (size_t)nc * 128);
  const float*  Wh = W + h * 32;              // uniform base
  float acc[32];
  #pragma unroll
  for (int j = 0; j < 32; ++j) acc[j] = 0.f;
  float4 xv = xr[0];
  for (int kt = 0; kt < 32; ++kt) {
    float4 cur = xv;
    if (kt < 31) xv = xr[kt + 1];             // prefetch next 16B of x
    GEMM_STEP(Wh, (kt * 4 + 0) * 128, cur.x);
    GEMM_STEP(Wh, (kt * 4 + 1) * 128, cur.y);
    GEMM_STEP(Wh, (kt * 4 + 2) * 128, cur.z);
    GEMM_STEP(Wh, (kt * 4 + 3) * 128, cur.w);
  }
  if (n < NN) {
    __align__(16) __half hbuf[32];
    #pragma unroll
    for (int j = 0; j < 32; ++j) hbuf[j] = __float2half_rn(acc[j]);
    float4* dst = (float4*)(xlh + (size_t)n * 128 + h * 32);   // 64 B, 16B-aligned
    #pragma unroll
    for (int i = 0; i < 4; ++i) dst[i] = ((const float4*)hbuf)[i];
    float ss = 0.f, sd = 0.f;
    #pragma unroll
    for (int j = 0; j < 32; ++j) {
      ss += acc[j] * att_src[h * 32 + j];     // uniform
      sd += acc[j] * att_dst[h * 32 + j];
    }
    asrc[n * 4 + h] = ss;
    adst[n * 4 + h] = sd;
  }
}

// -------------------- layer-1 aggregation (fused softmax), batch-4 pipelined ------------
__global__ __launch_bounds__(256) void k_agg1(
    const int* __restrict__ rowptr, const int* __restrict__ csr_src,
    const float* __restrict__ ea_slot, const float* __restrict__ asrc,
    const float* __restrict__ adst, const float* __restrict__ coef,
    const __half* __restrict__ xlh, float* __restrict__ out1) {
  int n = blockIdx.x * 8 + (threadIdx.x >> 5);
  if (n >= NN) return;
  int l = threadIdx.x & 31;
  int c4 = l << 2;                    // 4 channels per lane, 32 lanes = 128 ch
  int h = l >> 3;                     // head of this channel group
  float cf = coef[h];
  float ad = adst[(size_t)n * 4 + h];
  int r0 = rowptr[n], r1 = rowptr[n + 1];   // r1 > r0 (self-loop)
  float a0 = 0.f, a1 = 0.f, a2 = 0.f, a3 = 0.f, den = 0.f;
  for (int j = r0; j < r1; j += 4) {
    int sv[4]; float eav[4], asv[4]; uint2 raw[4];
    #pragma unroll
    for (int k = 0; k < 4; ++k) {
      int jj = (j + k < r1) ? (j + k) : (r1 - 1);
      sv[k] = csr_src[jj];
      eav[k] = ea_slot[jj];
    }
    #pragma unroll
    for (int k = 0; k < 4; ++k) {
      asv[k] = asrc[(size_t)sv[k] * 4 + h];
      raw[k] = *(const uint2*)(xlh + (size_t)sv[k] * 128 + c4);   // 4 halfs
    }
    #pragma unroll
    for (int k = 0; k < 4; ++k) {
      float alpha = asv[k] + ad + eav[k] * cf;
      alpha = alpha > 0.f ? alpha : NEG * alpha;
      float ex = (j + k < r1) ? __expf(alpha) : 0.f;   // tail mask
      __half2 p0, p1;
      *(unsigned int*)&p0 = raw[k].x;
      *(unsigned int*)&p1 = raw[k].y;
      float2 f0 = __half22float2(p0), f1 = __half22float2(p1);
      a0 += ex * f0.x;
      a1 += ex * f0.y;
      a2 += ex * f1.x;
      a3 += ex * f1.y;
      den += ex;
    }
  }
  float inv = 1.f / den;
  *(float4*)(out1 + (size_t)n * 128 + c4) = make_float4(a0 * inv, a1 * inv, a2 * inv, a3 * inv);
}

// -------------------- layer-2 GEMM: hl(fp16) = elu(out1+bias1) @ W2, plus logits --------
__global__ __launch_bounds__(64) void k_lin2(
    const float* __restrict__ out1, const float* __restrict__ bias1,
    const float* __restrict__ W2,
    const float* __restrict__ as2w, const float* __restrict__ ad2w,
    __half* __restrict__ hlh, float* __restrict__ asrc2, float* __restrict__ adst2) {
  const int n  = blockIdx.x * 64 + threadIdx.x;
  const int nc = n < NN ? n : NN - 1;
  const float4* xr = (const float4*)(out1 + (size_t)nc * 128);
  const float4* br = (const float4*)bias1;   // uniform
  float acc[32];
  #pragma unroll
  for (int j = 0; j < 32; ++j) acc[j] = 0.f;
  float4 xv = xr[0];
  for (int kt = 0; kt < 32; ++kt) {
    float4 cur = xv;
    if (kt < 31) xv = xr[kt + 1];
    float4 b = br[kt];                       // uniform
    cur.x += b.x; cur.y += b.y; cur.z += b.z; cur.w += b.w;
    cur.x = cur.x > 0.f ? cur.x : (expf(cur.x) - 1.f);   // ELU (once per element)
    cur.y = cur.y > 0.f ? cur.y : (expf(cur.y) - 1.f);
    cur.z = cur.z > 0.f ? cur.z : (expf(cur.z) - 1.f);
    cur.w = cur.w > 0.f ? cur.w : (expf(cur.w) - 1.f);
    GEMM_STEP(W2, (kt * 4 + 0) * 32, cur.x);
    GEMM_STEP(W2, (kt * 4 + 1) * 32, cur.y);
    GEMM_STEP(W2, (kt * 4 + 2) * 32, cur.z);
    GEMM_STEP(W2, (kt * 4 + 3) * 32, cur.w);
  }
  if (n < NN) {
    __align__(16) __half hbuf[32];
    #pragma unroll
    for (int j = 0; j < 32; ++j) hbuf[j] = __float2half_rn(acc[j]);
    float4* dst = (float4*)(hlh + (size_t)n * 32);   // 64 B
    #pragma unroll
    for (int i = 0; i < 4; ++i) dst[i] = ((const float4*)hbuf)[i];
    float ps = 0.f, pd = 0.f;
    #pragma unroll
    for (int j = 0; j < 32; ++j) {
      ps += acc[j] * as2w[j];                // uniform
      pd += acc[j] * ad2w[j];
    }
    asrc2[n] = ps;
    adst2[n] = pd;
  }
}

// -------------------- layer-2 aggregation (fused softmax), batch-4 pipelined ------------
__global__ __launch_bounds__(256) void k_agg2(
    const int* __restrict__ rowptr, const int* __restrict__ csr_src,
    const float* __restrict__ ea_slot, const float* __restrict__ asrc2,
    const float* __restrict__ adst2, const float* __restrict__ coef,
    const __half* __restrict__ hlh, const float* __restrict__ bias2,
    float* __restrict__ out) {
  int n = blockIdx.x * 32 + (threadIdx.x >> 3);
  if (n >= NN) return;
  int c4 = (threadIdx.x & 7) << 2;
  float cf = coef[4];
  float ad = adst2[n];
  int r0 = rowptr[n], r1 = rowptr[n + 1];
  float a0 = 0.f, a1 = 0.f, a2 = 0.f, a3 = 0.f, den = 0.f;
  for (int j = r0; j < r1; j += 4) {
    int sv[4]; float eav[4], asv[4]; uint2 raw[4];
    #pragma unroll
    for (int k = 0; k < 4; ++k) {
      int jj = (j + k < r1) ? (j + k) : (r1 - 1);
      sv[k] = csr_src[jj];
      eav[k] = ea_slot[jj];
    }
    #pragma unroll
    for (int k = 0; k < 4; ++k) {
      asv[k] = asrc2[sv[k]];
      raw[k] = *(const uint2*)(hlh + (size_t)sv[k] * 32 + c4);   // 4 halfs
    }
    #pragma unroll
    for (int k = 0; k < 4; ++k) {
      float alpha = asv[k] + ad + eav[k] * cf;
      alpha = alpha > 0.f ? alpha : NEG * alpha;
      float ex = (j + k < r1) ? __expf(alpha) : 0.f;   // tail mask
      __half2 p0, p1;
      *(unsigned int*)&p0 = raw[k].x;
      *(unsigned int*)&p1 = raw[k].y;
      float2 f0 = __half22float2(p0), f1 = __half22float2(p1);
      a0 += ex * f0.x;
      a1 += ex * f0.y;
      a2 += ex * f1.x;
      a3 += ex * f1.y;
      den += ex;
    }
  }
  float inv = 1.f / den;
  float4 b = *(const float4*)(bias2 + c4);
  *(float4*)(out + (size_t)n * 32 + c4) =
      make_float4(a0 * inv + b.x, a1 * inv + b.y, a2 * inv + b.z, a3 * inv + b.w);
}

extern "C" void kernel_launch(void* const* d_in, const int* in_sizes, int n_in,
                              void* d_out, int out_size, void* d_ws, size_t ws_size,
                              hipStream_t stream) {
  const float* x        = (const float*)d_in[0];
  const int*   ei       = (const int*)d_in[1];
  const float* eattr    = (const float*)d_in[2];
  const float* lin1_w   = (const float*)d_in[3];
  const float* att1_src = (const float*)d_in[4];
  const float* att1_dst = (const float*)d_in[5];
  const float* lin1_ew  = (const float*)d_in[6];
  const float* att1_e   = (const float*)d_in[7];
  const float* bias1    = (const float*)d_in[8];
  const float* lin2_w   = (const float*)d_in[9];
  const float* att2_src = (const float*)d_in[10];
  const float* att2_dst = (const float*)d_in[11];
  const float* lin2_ew  = (const float*)d_in[12];
  const float* att2_e   = (const float*)d_in[13];
  const float* bias2    = (const float*)d_in[14];
  float* out = (float*)d_out;
  float* ws  = (float*)d_ws;
  int*   wsi = (int*)d_ws;

  int*    deg     = wsi + O_DEG;
  float*  easum   = ws + O_EASUM;
  float*  coef    = ws + O_COEF;
  int*    rowptr  = wsi + O_ROWPTR;
  int*    cursor  = wsi + O_CURSOR;
  int*    blksum  = wsi + O_BLKSUM;
  int*    blkoff  = wsi + O_BLKOFF;
  int*    csr_src = wsi + O_CSRSRC;
  float*  ea_slot = ws + O_EASLOT;
  float*  asrc1   = ws + O_ASRC1;
  float*  adst1   = ws + O_ADST1;
  __half* xlh     = (__half*)(ws + O_XLH);
  float*  out1    = ws + O_OUT1;
  __half* hlh     = (__half*)(ws + O_HLH);
  float*  asrc2   = ws + O_ASRC2;
  float*  adst2   = ws + O_ADST2;

  // zero deg/easum (ws poisoned 0xAA each call)
  hipMemsetAsync(ws, 0, (size_t)ZERO_ELEMS * sizeof(float), stream);

  k_ea_count<<<256, 256, 0, stream>>>(eattr, ei, easum, deg);

  // CSR build (dst-sorted): multi-block scan; self-loops written deterministically
  k_scan_blk<<<SCAN_BLOCKS, 256, 0, stream>>>(deg, rowptr, blksum);
  k_scan_top<<<1, 256, 0, stream>>>(blksum, blkoff, lin1_ew, att1_e, lin2_ew, att2_e, coef);
  k_scan_add<<<SCAN_BLOCKS, 256, 0, stream>>>(rowptr, cursor, blkoff, deg, easum, csr_src, ea_slot);

  // FUSED: layer-1 GEMM (blocks 0..LIN1B) ∥ CSR fill (blocks LIN1B..LIN1B+FILLB)
  k_fused<<<LIN1B + FILLB, 64, 0, stream>>>(x, lin1_w, att1_src, att1_dst, xlh, asrc1, adst1,
                                            ei, eattr, cursor, csr_src, ea_slot);

  k_agg1<<<(NN + 7) / 8, 256, 0, stream>>>(rowptr, csr_src, ea_slot, asrc1, adst1, coef, xlh, out1);

  // layer 2
  k_lin2<<<(NN + 63) / 64, 64, 0, stream>>>(out1, bias1, lin2_w, att2_src, att2_dst, hlh, asrc2, adst2);
  k_agg2<<<(NN + 31) / 32, 256, 0, stream>>>(rowptr, csr_src, ea_slot, asrc2, adst2, coef, hlh, bias2, out);
}